// Round 1
// baseline (633.563 us; speedup 1.0000x reference)
//
#include <hip/hip_runtime.h>

#define NFREQ 2049   // 4096/2 + 1

using cf = float2;

// ---------------------------------------------------------------------------
// K1: projection GEMM  out = X @ W^T + b
//   X: [32768, 256] row-major (B=8 batches of N=4096 rows)
//   W: [256, 256] row-major  -> out[m,j] = dot(X[m,:], W[j,:]) + b[j]
// mode 0/1: write transposed  dst[(b*256 + j)*4096 + n]   (QL / KL)
// mode 2  : write natural     dst[m*256 + j]              (VL)
// ---------------------------------------------------------------------------
__global__ __launch_bounds__(256) void gemm_proj(
    const float* __restrict__ X, const float* __restrict__ W,
    const float* __restrict__ bias, float* __restrict__ dst, int mode)
{
  __shared__ float As[32][65];
  __shared__ float Bs[32][65];
  __shared__ float Tr[64][65];
  const int m0 = blockIdx.x * 64;
  const int j0 = blockIdx.y * 64;
  const int tid = threadIdx.x;
  const int tx = tid & 15, ty = tid >> 4;
  float acc[4][4] = {};

  for (int kk0 = 0; kk0 < 256; kk0 += 32) {
    #pragma unroll
    for (int r = 0; r < 2; r++) {
      int v = tid + r * 256;          // 0..511
      int row = v >> 3;               // 0..63
      int c4 = (v & 7) * 4;           // 0..28
      float4 xa = *(const float4*)(X + (size_t)(m0 + row) * 256 + kk0 + c4);
      As[c4 + 0][row] = xa.x; As[c4 + 1][row] = xa.y;
      As[c4 + 2][row] = xa.z; As[c4 + 3][row] = xa.w;
      float4 wb = *(const float4*)(W + (size_t)(j0 + row) * 256 + kk0 + c4);
      Bs[c4 + 0][row] = wb.x; Bs[c4 + 1][row] = wb.y;
      Bs[c4 + 2][row] = wb.z; Bs[c4 + 3][row] = wb.w;
    }
    __syncthreads();
    #pragma unroll
    for (int kk = 0; kk < 32; kk++) {
      float a_[4], b_[4];
      #pragma unroll
      for (int i = 0; i < 4; i++) a_[i] = As[kk][ty * 4 + i];
      #pragma unroll
      for (int j = 0; j < 4; j++) b_[j] = Bs[kk][tx * 4 + j];
      #pragma unroll
      for (int i = 0; i < 4; i++)
        #pragma unroll
        for (int j = 0; j < 4; j++)
          acc[i][j] += a_[i] * b_[j];
    }
    __syncthreads();
  }

  #pragma unroll
  for (int j = 0; j < 4; j++) {
    float bj = bias[j0 + tx * 4 + j];
    #pragma unroll
    for (int i = 0; i < 4; i++) acc[i][j] += bj;
  }

  if (mode == 2) {
    #pragma unroll
    for (int i = 0; i < 4; i++) {
      float4 o = make_float4(acc[i][0], acc[i][1], acc[i][2], acc[i][3]);
      *(float4*)(dst + (size_t)(m0 + ty * 4 + i) * 256 + j0 + tx * 4) = o;
    }
  } else {
    #pragma unroll
    for (int i = 0; i < 4; i++)
      #pragma unroll
      for (int j = 0; j < 4; j++)
        Tr[ty * 4 + i][tx * 4 + j] = acc[i][j];
    __syncthreads();
    const int b = m0 >> 12;          // batch (4096 % 64 == 0, uniform per block)
    const int n0 = m0 & 4095;
    #pragma unroll
    for (int k = 0; k < 4; k++) {
      int v = tid + k * 256;          // 0..1023
      int col = v >> 4;               // 0..63  (output channel within tile)
      int m4 = (v & 15) * 4;          // 0..60  (n within tile, x4)
      float4 o = make_float4(Tr[m4 + 0][col], Tr[m4 + 1][col],
                             Tr[m4 + 2][col], Tr[m4 + 3][col]);
      *(float4*)(dst + ((size_t)(b * 256 + j0 + col)) * 4096 + n0 + m4) = o;
    }
  }
}

// ---------------------------------------------------------------------------
// Radix-2 DIT FFT stages over 4096 complex points in LDS, 256 threads.
// Input must be loaded bit-reversed; output natural order.
// sign = -1: forward (e^{-i...}); +1: inverse (unscaled).
// ---------------------------------------------------------------------------
__device__ inline void fft_stages(cf* X, int tid, float sign)
{
  for (int s = 1; s <= 12; s++) {
    const int half = 1 << (s - 1);
    __syncthreads();
    #pragma unroll 2
    for (int i = 0; i < 8; i++) {
      int t = tid + i * 256;                    // butterfly id 0..2047
      int j = t & (half - 1);
      int k = ((t >> (s - 1)) << s) + j;
      float ang = sign * 6.283185307179586f * (float)j / (float)(2 * half);
      float sn, cs;
      __sincosf(ang, &sn, &cs);
      cf a = X[k];
      cf b = X[k + half];
      float tbx = cs * b.x - sn * b.y;
      float tby = cs * b.y + sn * b.x;
      X[k]        = make_float2(a.x + tbx, a.y + tby);
      X[k + half] = make_float2(a.x - tbx, a.y - tby);
    }
  }
  __syncthreads();
}

// K2: forward FFT of one real column (length 4096), store f = 0..2048
__global__ __launch_bounds__(256) void fft_fwd(
    const float* __restrict__ src_base, cf* __restrict__ dst_base)
{
  __shared__ cf X[4096];
  const int col = blockIdx.x;                      // 0..2047 = b*256 + h*32 + d
  const float* src = src_base + (size_t)col * 4096;
  cf* dst = dst_base + (size_t)col * NFREQ;
  const int tid = threadIdx.x;
  #pragma unroll
  for (int i = 0; i < 16; i++) {
    int n = tid + i * 256;
    int r = __brev((unsigned)n) >> 20;             // 12-bit reversal
    X[r] = make_float2(src[n], 0.0f);
  }
  fft_stages(X, tid, -1.0f);
  for (int f = tid; f < NFREQ; f += 256) dst[f] = X[f];
}

// ---------------------------------------------------------------------------
// K3: frequency-domain circular convolution along d (32), in place over Qf.
//   C[f,d] = sum_e Qf[f,e] * Kf[f,(d-e) mod 32]
// Freq layout: [bh*32 + d][f], f = 0..2048, stride NFREQ complex.
// ---------------------------------------------------------------------------
__global__ __launch_bounds__(256) void freq_conv(
    cf* __restrict__ Qf, const cf* __restrict__ Kf)
{
  __shared__ cf Qs[32][64];
  __shared__ cf Ks[32][64];
  const int f0 = blockIdx.x * 64;
  const int bh = blockIdx.y;                       // 0..63 = b*8 + h
  const int tid = threadIdx.x;
  #pragma unroll
  for (int i = 0; i < 8; i++) {
    int v = tid + i * 256;
    int e = v >> 6, fl = v & 63;
    int f = f0 + fl;
    if (f < NFREQ) {
      Qs[e][fl] = Qf[(size_t)(bh * 32 + e) * NFREQ + f];
      Ks[e][fl] = Kf[(size_t)(bh * 32 + e) * NFREQ + f];
    }
  }
  __syncthreads();
  #pragma unroll
  for (int i = 0; i < 8; i++) {
    int v = tid + i * 256;
    int d = v >> 6, fl = v & 63;
    int f = f0 + fl;
    cf acc = make_float2(0.0f, 0.0f);
    #pragma unroll
    for (int e = 0; e < 32; e++) {
      cf qv = Qs[e][fl];
      cf kv = Ks[(d - e) & 31][fl];
      acc.x += qv.x * kv.x - qv.y * kv.y;
      acc.y += qv.x * kv.y + qv.y * kv.x;
    }
    if (f < NFREQ) Qf[(size_t)(bh * 32 + d) * NFREQ + f] = acc;
  }
}

// K4: inverse FFT of one column (hermitian half-spectrum in), real part out
__global__ __launch_bounds__(256) void fft_inv(
    const cf* __restrict__ Cf, float* __restrict__ attn)
{
  __shared__ cf X[4096];
  const int col = blockIdx.x;
  const cf* src = Cf + (size_t)col * NFREQ;
  float* dst = attn + (size_t)col * 4096;
  const int tid = threadIdx.x;
  for (int f = tid; f < NFREQ; f += 256) {
    cf v = src[f];
    int r = __brev((unsigned)f) >> 20;
    X[r] = v;
    if (f != 0 && f != 2048) {
      int r2 = __brev((unsigned)(4096 - f)) >> 20;
      X[r2] = make_float2(v.x, -v.y);              // conj mirror
    }
  }
  fft_stages(X, tid, +1.0f);
  const float inv = 1.0f / 4096.0f;
  #pragma unroll
  for (int i = 0; i < 16; i++) {
    int n = tid + i * 256;
    dst[n] = X[n].x * inv;
  }
}

// ---------------------------------------------------------------------------
// K5: softmax over d (32) + value gate + residual + LayerNorm(256)
// attn layout [b*256 + h*32 + d][n]; tile of 32 n transposed through LDS.
// ---------------------------------------------------------------------------
__global__ __launch_bounds__(256) void finalize_kernel(
    const float* __restrict__ attn, const float* __restrict__ VL,
    const float* __restrict__ vin, const float* __restrict__ gamma,
    const float* __restrict__ beta, float* __restrict__ out)
{
  __shared__ float At[256][33];
  __shared__ float red[8];
  const int n0 = blockIdx.x * 32;
  const int b = blockIdx.y;
  const int tid = threadIdx.x;
  #pragma unroll
  for (int i = 0; i < 32; i++) {
    int v = tid + i * 256;
    int hd = v >> 5, nn = v & 31;
    At[hd][nn] = attn[(size_t)(b * 256 + hd) * 4096 + n0 + nn];
  }
  __syncthreads();
  const float g = gamma[tid];
  const float bt = beta[tid];
  const int wave = tid >> 6, lane = tid & 63;
  for (int nn = 0; nn < 32; nn++) {
    const int n = n0 + nn;
    float a = At[tid][nn];
    // softmax over the 32-lane head group
    float mx = a;
    #pragma unroll
    for (int off = 16; off >= 1; off >>= 1) mx = fmaxf(mx, __shfl_xor(mx, off, 32));
    float e = __expf(a - mx);
    float s = e;
    #pragma unroll
    for (int off = 16; off >= 1; off >>= 1) s += __shfl_xor(s, off, 32);
    float p = e / s;
    const size_t base = ((size_t)b * 4096 + n) * 256 + tid;
    float o = VL[base] * p + vin[base];
    // LayerNorm over 256 channels
    float s1 = o, s2 = o * o;
    #pragma unroll
    for (int off = 32; off >= 1; off >>= 1) {
      s1 += __shfl_xor(s1, off, 64);
      s2 += __shfl_xor(s2, off, 64);
    }
    if (lane == 0) { red[wave * 2] = s1; red[wave * 2 + 1] = s2; }
    __syncthreads();
    float S1 = red[0] + red[2] + red[4] + red[6];
    float S2 = red[1] + red[3] + red[5] + red[7];
    __syncthreads();
    float mu = S1 * (1.0f / 256.0f);
    float var = S2 * (1.0f / 256.0f) - mu * mu;
    float r = rsqrtf(var + 1e-5f);
    out[base] = (o - mu) * r * g + bt;
  }
}

// ---------------------------------------------------------------------------
extern "C" void kernel_launch(void* const* d_in, const int* in_sizes, int n_in,
                              void* d_out, int out_size, void* d_ws, size_t ws_size,
                              hipStream_t stream)
{
  const float* q  = (const float*)d_in[0];
  const float* k  = (const float*)d_in[1];
  const float* v  = (const float*)d_in[2];
  const float* Wq = (const float*)d_in[3];
  const float* bq = (const float*)d_in[4];
  const float* Wk = (const float*)d_in[5];
  const float* bk = (const float*)d_in[6];
  const float* Wv = (const float*)d_in[7];
  const float* bv = (const float*)d_in[8];
  const float* ln_gamma = (const float*)d_in[9];
  const float* ln_beta  = (const float*)d_in[10];
  float* out = (float*)d_out;

  // Workspace layout (floats). Total = 41,951,232 floats = ~167.8 MB.
  float* ws = (float*)d_ws;
  float* QL = ws;                               // [2048][4096]  (b*256+ch major)
  float* KL = QL + (size_t)8388608;             // [2048][4096]
  float* VL = KL + (size_t)8388608;             // [32768][256]
  cf* Qf = (cf*)(VL + (size_t)8388608);         // [2048][2049] complex
  cf* Kf = Qf + (size_t)2048 * NFREQ;           // [2048][2049] complex
  float* attn = QL;                             // reuse QL after fwd FFT

  gemm_proj<<<dim3(512, 4), 256, 0, stream>>>(q, Wq, bq, QL, 0);
  gemm_proj<<<dim3(512, 4), 256, 0, stream>>>(k, Wk, bk, KL, 1);
  gemm_proj<<<dim3(512, 4), 256, 0, stream>>>(v, Wv, bv, VL, 2);

  fft_fwd<<<2048, 256, 0, stream>>>(QL, Qf);
  fft_fwd<<<2048, 256, 0, stream>>>(KL, Kf);

  freq_conv<<<dim3(33, 64), 256, 0, stream>>>(Qf, Kf);

  fft_inv<<<2048, 256, 0, stream>>>(Qf, attn);

  finalize_kernel<<<dim3(128, 8), 256, 0, stream>>>(attn, VL, v, ln_gamma,
                                                    ln_beta, out);
}

// Round 2
// 511.228 us; speedup vs baseline: 1.2393x; 1.2393x over previous
//
#include <hip/hip_runtime.h>

#define NFREQ 2049   // 4096/2 + 1

using cf = float2;

// ---------------------------------------------------------------------------
// K1: projection GEMM  out = X @ W^T + b
//   X: [32768, 256] row-major (B=8 batches of N=4096 rows)
//   W: [256, 256] row-major  -> out[m,j] = dot(X[m,:], W[j,:]) + b[j]
// mode 0/1: write transposed  dst[(b*256 + j)*4096 + n]   (QL / KL)
// mode 2  : write natural     dst[m*256 + j]              (VL)
// Tile: 128 m x 128 j per block (256 thr), 8x8 per thread, K-chunk 32.
// ---------------------------------------------------------------------------
__global__ __launch_bounds__(256) void gemm_proj(
    const float* __restrict__ X, const float* __restrict__ W,
    const float* __restrict__ bias, float* __restrict__ dst, int mode)
{
  __shared__ float smem[8704];                 // 34,816 B
  float (*As)[132] = (float(*)[132])smem;      // [32][132]
  float (*Bs)[132] = (float(*)[132])(smem + 4224);
  float (*Tr)[136] = (float(*)[136])smem;      // [64][136] epilogue reuse

  const int m0 = blockIdx.x * 128;
  const int j0 = blockIdx.y * 128;
  const int tid = threadIdx.x;
  const int tx = tid & 15, ty = tid >> 4;

  float acc[2][2][4][4] = {};                  // [mh][jh][i][jj]

  for (int k0 = 0; k0 < 256; k0 += 32) {
    #pragma unroll
    for (int r = 0; r < 4; r++) {
      int v = tid + r * 256;                   // 0..1023
      int row = v >> 3;                        // 0..127
      int c4 = (v & 7) * 4;                    // 0..28
      float4 xa = *(const float4*)(X + (size_t)(m0 + row) * 256 + k0 + c4);
      As[c4 + 0][row] = xa.x; As[c4 + 1][row] = xa.y;
      As[c4 + 2][row] = xa.z; As[c4 + 3][row] = xa.w;
      float4 wb = *(const float4*)(W + (size_t)(j0 + row) * 256 + k0 + c4);
      Bs[c4 + 0][row] = wb.x; Bs[c4 + 1][row] = wb.y;
      Bs[c4 + 2][row] = wb.z; Bs[c4 + 3][row] = wb.w;
    }
    __syncthreads();
    #pragma unroll 4
    for (int kk = 0; kk < 32; kk++) {
      float4 a0 = *(const float4*)&As[kk][tx * 4];
      float4 a1 = *(const float4*)&As[kk][64 + tx * 4];
      float4 b0 = *(const float4*)&Bs[kk][ty * 4];
      float4 b1 = *(const float4*)&Bs[kk][64 + ty * 4];
      float am[2][4] = {{a0.x, a0.y, a0.z, a0.w}, {a1.x, a1.y, a1.z, a1.w}};
      float bn[2][4] = {{b0.x, b0.y, b0.z, b0.w}, {b1.x, b1.y, b1.z, b1.w}};
      #pragma unroll
      for (int mh = 0; mh < 2; mh++)
        #pragma unroll
        for (int jh = 0; jh < 2; jh++)
          #pragma unroll
          for (int i = 0; i < 4; i++)
            #pragma unroll
            for (int jj = 0; jj < 4; jj++)
              acc[mh][jh][i][jj] += am[mh][i] * bn[jh][jj];
    }
    __syncthreads();
  }

  #pragma unroll
  for (int jh = 0; jh < 2; jh++)
    #pragma unroll
    for (int jj = 0; jj < 4; jj++) {
      float bj = bias[j0 + jh * 64 + ty * 4 + jj];
      #pragma unroll
      for (int mh = 0; mh < 2; mh++)
        #pragma unroll
        for (int i = 0; i < 4; i++)
          acc[mh][jh][i][jj] += bj;
    }

  if (mode == 2) {
    #pragma unroll
    for (int mh = 0; mh < 2; mh++)
      #pragma unroll
      for (int i = 0; i < 4; i++) {
        int m = m0 + mh * 64 + tx * 4 + i;
        #pragma unroll
        for (int jh = 0; jh < 2; jh++) {
          float4 o = make_float4(acc[mh][jh][i][0], acc[mh][jh][i][1],
                                 acc[mh][jh][i][2], acc[mh][jh][i][3]);
          *(float4*)(dst + (size_t)m * 256 + j0 + jh * 64 + ty * 4) = o;
        }
      }
  } else {
    const int b = m0 >> 12;
    const int n0 = m0 & 4095;
    for (int jh = 0; jh < 2; jh++) {
      if (jh) __syncthreads();
      #pragma unroll
      for (int jj = 0; jj < 4; jj++)
        #pragma unroll
        for (int mh = 0; mh < 2; mh++) {
          float4 o = make_float4(acc[mh][jh][0][jj], acc[mh][jh][1][jj],
                                 acc[mh][jh][2][jj], acc[mh][jh][3][jj]);
          *(float4*)&Tr[ty * 4 + jj][mh * 64 + tx * 4] = o;
        }
      __syncthreads();
      #pragma unroll
      for (int r = 0; r < 8; r++) {
        int v = tid + r * 256;                 // 0..2047
        int jl = v >> 5;                       // 0..63
        int m4 = (v & 31) * 4;                 // 0..124
        float4 o = *(const float4*)&Tr[jl][m4];
        *(float4*)(dst + (size_t)(b * 256 + j0 + jh * 64 + jl) * 4096 + n0 + m4) = o;
      }
    }
  }
}

// ---------------------------------------------------------------------------
// Radix-2 DIT FFT over 4096 complex points in LDS, 256 threads.
// Input loaded bit-reversed; output natural order. sign=-1 fwd, +1 inv.
// ---------------------------------------------------------------------------
__device__ inline void fft_stages(cf* X, int tid, float sign)
{
  for (int s = 1; s <= 12; s++) {
    const int half = 1 << (s - 1);
    __syncthreads();
    #pragma unroll 2
    for (int i = 0; i < 8; i++) {
      int t = tid + i * 256;                   // butterfly 0..2047
      int j = t & (half - 1);
      int k = ((t >> (s - 1)) << s) + j;
      float ang = sign * 6.283185307179586f * (float)j / (float)(2 * half);
      float sn, cs;
      __sincosf(ang, &sn, &cs);
      cf a = X[k];
      cf b = X[k + half];
      float tbx = cs * b.x - sn * b.y;
      float tby = cs * b.y + sn * b.x;
      X[k]        = make_float2(a.x + tbx, a.y + tby);
      X[k + half] = make_float2(a.x - tbx, a.y - tby);
    }
  }
  __syncthreads();
}

// K2: forward FFT of TWO real columns packed as one complex FFT.
// cols (2c, 2c+1); X1=(Z[f]+conj(Z[N-f]))/2, X2=(Z[f]-conj(Z[N-f]))/(2i)
__global__ __launch_bounds__(256) void fft_fwd(
    const float* __restrict__ src_base, cf* __restrict__ dst_base)
{
  __shared__ cf X[4096];
  const int c0 = blockIdx.x * 2;               // 0..2046 even
  const float* s0 = src_base + (size_t)c0 * 4096;
  const float* s1 = s0 + 4096;
  const int tid = threadIdx.x;
  #pragma unroll
  for (int i = 0; i < 16; i++) {
    int n = tid + i * 256;
    int r = __brev((unsigned)n) >> 20;         // 12-bit reversal
    X[r] = make_float2(s0[n], s1[n]);
  }
  fft_stages(X, tid, -1.0f);
  cf* d0 = dst_base + (size_t)c0 * NFREQ;
  cf* d1 = d0 + NFREQ;
  for (int f = tid; f <= 2048; f += 256) {
    cf Zf = X[f];
    cf Zm = X[(4096 - f) & 4095];
    d0[f] = make_float2(0.5f * (Zf.x + Zm.x), 0.5f * (Zf.y - Zm.y));
    d1[f] = make_float2(0.5f * (Zf.y + Zm.y), 0.5f * (Zm.x - Zf.x));
  }
}

// ---------------------------------------------------------------------------
// K3: frequency-domain circular convolution along d (32), in place over Qf.
// ---------------------------------------------------------------------------
__global__ __launch_bounds__(256) void freq_conv(
    cf* __restrict__ Qf, const cf* __restrict__ Kf)
{
  __shared__ cf Qs[32][64];
  __shared__ cf Ks[32][64];
  const int f0 = blockIdx.x * 64;
  const int bh = blockIdx.y;                   // 0..63
  const int tid = threadIdx.x;
  #pragma unroll
  for (int i = 0; i < 8; i++) {
    int v = tid + i * 256;
    int e = v >> 6, fl = v & 63;
    int f = f0 + fl;
    if (f < NFREQ) {
      Qs[e][fl] = Qf[(size_t)(bh * 32 + e) * NFREQ + f];
      Ks[e][fl] = Kf[(size_t)(bh * 32 + e) * NFREQ + f];
    }
  }
  __syncthreads();
  #pragma unroll
  for (int i = 0; i < 8; i++) {
    int v = tid + i * 256;
    int d = v >> 6, fl = v & 63;
    int f = f0 + fl;
    cf acc = make_float2(0.0f, 0.0f);
    #pragma unroll
    for (int e = 0; e < 32; e++) {
      cf qv = Qs[e][fl];
      cf kv = Ks[(d - e) & 31][fl];
      acc.x += qv.x * kv.x - qv.y * kv.y;
      acc.y += qv.x * kv.y + qv.y * kv.x;
    }
    if (f < NFREQ) Qf[(size_t)(bh * 32 + d) * NFREQ + f] = acc;
  }
}

// K4: inverse FFT of TWO hermitian half-spectra packed: Z = C1 + i*C2.
// z[n] real part -> col0, imag part -> col1.
__global__ __launch_bounds__(256) void fft_inv(
    const cf* __restrict__ Cf, float* __restrict__ attn)
{
  __shared__ cf X[4096];
  const int c0 = blockIdx.x * 2;
  const cf* s0 = Cf + (size_t)c0 * NFREQ;
  const cf* s1 = s0 + NFREQ;
  const int tid = threadIdx.x;
  for (int f = tid; f <= 2048; f += 256) {
    cf c1 = s0[f];
    cf c2 = s1[f];
    int r = __brev((unsigned)f) >> 20;
    X[r] = make_float2(c1.x - c2.y, c1.y + c2.x);
    if (f != 0 && f != 2048) {
      int r2 = __brev((unsigned)(4096 - f)) >> 20;
      X[r2] = make_float2(c1.x + c2.y, c2.x - c1.y);   // conj(C1)+i*conj(C2)
    }
  }
  fft_stages(X, tid, +1.0f);
  float* d0 = attn + (size_t)c0 * 4096;
  float* d1 = d0 + 4096;
  const float inv = 1.0f / 4096.0f;
  #pragma unroll
  for (int i = 0; i < 16; i++) {
    int n = tid + i * 256;
    cf z = X[n];
    d0[n] = z.x * inv;
    d1[n] = z.y * inv;
  }
}

// ---------------------------------------------------------------------------
// K5: softmax over d (32) + value gate + residual + LayerNorm(256)
// One barrier (after LDS transpose); each wave owns 8 n wave-locally.
// ---------------------------------------------------------------------------
__global__ __launch_bounds__(256) void finalize_kernel(
    const float* __restrict__ attn, const float* __restrict__ VL,
    const float* __restrict__ vin, const float* __restrict__ gamma,
    const float* __restrict__ beta, float* __restrict__ out)
{
  __shared__ float At[256][33];
  const int n0 = blockIdx.x * 32;
  const int b = blockIdx.y;
  const int tid = threadIdx.x;
  #pragma unroll
  for (int i = 0; i < 32; i++) {
    int v = tid + i * 256;
    int hd = v >> 5, nn = v & 31;
    At[hd][nn] = attn[(size_t)(b * 256 + hd) * 4096 + n0 + nn];
  }
  __syncthreads();
  const int wave = tid >> 6, lane = tid & 63;
  float g[4], bt[4];
  #pragma unroll
  for (int r = 0; r < 4; r++) { g[r] = gamma[64 * r + lane]; bt[r] = beta[64 * r + lane]; }

  for (int t = 0; t < 8; t++) {
    const int nn = wave * 8 + t;
    const int n = n0 + nn;
    float p[4];
    #pragma unroll
    for (int r = 0; r < 4; r++) {
      float a = At[64 * r + lane][nn];
      float mx = a;
      #pragma unroll
      for (int off = 16; off >= 1; off >>= 1) mx = fmaxf(mx, __shfl_xor(mx, off, 32));
      float e = __expf(a - mx);
      float s = e;
      #pragma unroll
      for (int off = 16; off >= 1; off >>= 1) s += __shfl_xor(s, off, 32);
      p[r] = e / s;
    }
    const size_t base = ((size_t)b * 4096 + n) * 256 + lane;
    float o[4];
    float s1 = 0.0f, s2 = 0.0f;
    #pragma unroll
    for (int r = 0; r < 4; r++) {
      o[r] = VL[base + 64 * r] * p[r] + vin[base + 64 * r];
      s1 += o[r];
      s2 += o[r] * o[r];
    }
    #pragma unroll
    for (int off = 32; off >= 1; off >>= 1) {
      s1 += __shfl_xor(s1, off, 64);
      s2 += __shfl_xor(s2, off, 64);
    }
    float mu = s1 * (1.0f / 256.0f);
    float var = s2 * (1.0f / 256.0f) - mu * mu;
    float rs = rsqrtf(var + 1e-5f);
    #pragma unroll
    for (int r = 0; r < 4; r++)
      out[base + 64 * r] = (o[r] - mu) * rs * g[r] + bt[r];
  }
}

// ---------------------------------------------------------------------------
extern "C" void kernel_launch(void* const* d_in, const int* in_sizes, int n_in,
                              void* d_out, int out_size, void* d_ws, size_t ws_size,
                              hipStream_t stream)
{
  const float* q  = (const float*)d_in[0];
  const float* k  = (const float*)d_in[1];
  const float* v  = (const float*)d_in[2];
  const float* Wq = (const float*)d_in[3];
  const float* bq = (const float*)d_in[4];
  const float* Wk = (const float*)d_in[5];
  const float* bk = (const float*)d_in[6];
  const float* Wv = (const float*)d_in[7];
  const float* bv = (const float*)d_in[8];
  const float* ln_gamma = (const float*)d_in[9];
  const float* ln_beta  = (const float*)d_in[10];
  float* out = (float*)d_out;

  float* ws = (float*)d_ws;
  float* QL = ws;                               // [2048][4096]
  float* KL = QL + (size_t)8388608;             // [2048][4096]
  float* VL = KL + (size_t)8388608;             // [32768][256]
  cf* Qf = (cf*)(VL + (size_t)8388608);         // [2048][2049] complex
  cf* Kf = Qf + (size_t)2048 * NFREQ;           // [2048][2049] complex
  float* attn = QL;                             // reuse QL after fwd FFT

  gemm_proj<<<dim3(256, 2), 256, 0, stream>>>(q, Wq, bq, QL, 0);
  gemm_proj<<<dim3(256, 2), 256, 0, stream>>>(k, Wk, bk, KL, 1);
  gemm_proj<<<dim3(256, 2), 256, 0, stream>>>(v, Wv, bv, VL, 2);

  fft_fwd<<<1024, 256, 0, stream>>>(QL, Qf);
  fft_fwd<<<1024, 256, 0, stream>>>(KL, Kf);

  freq_conv<<<dim3(33, 64), 256, 0, stream>>>(Qf, Kf);

  fft_inv<<<1024, 256, 0, stream>>>(Qf, attn);

  finalize_kernel<<<dim3(128, 8), 256, 0, stream>>>(attn, VL, v, ln_gamma,
                                                    ln_beta, out);
}

// Round 3
// 353.733 us; speedup vs baseline: 1.7911x; 1.4452x over previous
//
#include <hip/hip_runtime.h>

#define NFREQ 2049   // 4096/2 + 1

using cf = float2;
typedef __attribute__((ext_vector_type(8))) short short8;
typedef __attribute__((ext_vector_type(4))) float floatx4;

__device__ inline unsigned short bf16_rne(float x) {
  unsigned u = __float_as_uint(x);
  unsigned r = u + 0x7FFFu + ((u >> 16) & 1u);
  return (unsigned short)(r >> 16);
}
__device__ inline float bf16_to_f(unsigned short h) {
  return __uint_as_float(((unsigned)h) << 16);
}

// ---------------------------------------------------------------------------
// K1: projection GEMM  C = X @ W^T + b  via split-bf16 MFMA (3 passes).
//   X: [32768, 256], W: [256, 256] row-major.
// mode 0/1: dst[(b*256 + j)*4096 + n] (transposed). mode 2: dst[m*256 + j].
// Block: 256 thr, tile 128m x 64j, K-chunk 32. Grid (256, 4).
// ---------------------------------------------------------------------------
__global__ __launch_bounds__(256, 4) void gemm_proj(
    const float* __restrict__ X, const float* __restrict__ W,
    const float* __restrict__ bias, float* __restrict__ dst, int mode)
{
  // LDS: bf16 fragments laid out [quad][row][8] with quad stride = (rows+1)*8
  __shared__ __align__(16) unsigned short sm[12416];
  unsigned short* sAhi = sm;            // 4*129*8 = 4128
  unsigned short* sAlo = sm + 4128;
  unsigned short* sBhi = sm + 8256;     // 4*65*8  = 2080
  unsigned short* sBlo = sm + 10336;

  const int tid = threadIdx.x;
  const int m0 = blockIdx.x * 128;
  const int j0 = blockIdx.y * 64;
  const int wave = tid >> 6, lane = tid & 63;
  const int wm = wave & 1, wj = wave >> 1;
  const int lm = lane & 15, quad = lane >> 4;

  floatx4 acc[4][2] = {};

  for (int k0 = 0; k0 < 256; k0 += 32) {
    // prefetch globals into registers
    float4 xa[4], wb[2];
    #pragma unroll
    for (int r = 0; r < 4; r++) {
      int v = tid + r * 256;                    // 0..1023
      int row = v >> 3, c4 = (v & 7) * 4;
      xa[r] = *(const float4*)(X + (size_t)(m0 + row) * 256 + k0 + c4);
    }
    #pragma unroll
    for (int r = 0; r < 2; r++) {
      int v = tid + r * 256;                    // 0..511
      int row = v >> 3, c4 = (v & 7) * 4;
      wb[r] = *(const float4*)(W + (size_t)(j0 + row) * 256 + k0 + c4);
    }
    __syncthreads();                            // LDS free (prev chunk read)
    #pragma unroll
    for (int r = 0; r < 4; r++) {
      int v = tid + r * 256;
      int row = v >> 3, c4 = (v & 7) * 4;
      int q = c4 >> 3, off = c4 & 7;
      float f[4] = {xa[r].x, xa[r].y, xa[r].z, xa[r].w};
      unsigned short h[4], l[4];
      #pragma unroll
      for (int i = 0; i < 4; i++) {
        h[i] = bf16_rne(f[i]);
        l[i] = bf16_rne(f[i] - bf16_to_f(h[i]));
      }
      int idx = ((q * 129 + row) << 3) + off;
      *(uint2*)&sAhi[idx] = make_uint2((unsigned)h[0] | ((unsigned)h[1] << 16),
                                       (unsigned)h[2] | ((unsigned)h[3] << 16));
      *(uint2*)&sAlo[idx] = make_uint2((unsigned)l[0] | ((unsigned)l[1] << 16),
                                       (unsigned)l[2] | ((unsigned)l[3] << 16));
    }
    #pragma unroll
    for (int r = 0; r < 2; r++) {
      int v = tid + r * 256;
      int row = v >> 3, c4 = (v & 7) * 4;
      int q = c4 >> 3, off = c4 & 7;
      float f[4] = {wb[r].x, wb[r].y, wb[r].z, wb[r].w};
      unsigned short h[4], l[4];
      #pragma unroll
      for (int i = 0; i < 4; i++) {
        h[i] = bf16_rne(f[i]);
        l[i] = bf16_rne(f[i] - bf16_to_f(h[i]));
      }
      int idx = ((q * 65 + row) << 3) + off;
      *(uint2*)&sBhi[idx] = make_uint2((unsigned)h[0] | ((unsigned)h[1] << 16),
                                       (unsigned)h[2] | ((unsigned)h[3] << 16));
      *(uint2*)&sBlo[idx] = make_uint2((unsigned)l[0] | ((unsigned)l[1] << 16),
                                       (unsigned)l[2] | ((unsigned)l[3] << 16));
    }
    __syncthreads();

    short8 ahi[4], alo[4], bhi[2], blo[2];
    #pragma unroll
    for (int mf = 0; mf < 4; mf++) {
      int row = wm * 64 + mf * 16 + lm;
      int idx = ((quad * 129 + row) << 3);
      ahi[mf] = *(const short8*)&sAhi[idx];
      alo[mf] = *(const short8*)&sAlo[idx];
    }
    #pragma unroll
    for (int jf = 0; jf < 2; jf++) {
      int row = wj * 32 + jf * 16 + lm;
      int idx = ((quad * 65 + row) << 3);
      bhi[jf] = *(const short8*)&sBhi[idx];
      blo[jf] = *(const short8*)&sBlo[idx];
    }
    #pragma unroll
    for (int mf = 0; mf < 4; mf++)
      #pragma unroll
      for (int jf = 0; jf < 2; jf++) {
        acc[mf][jf] = __builtin_amdgcn_mfma_f32_16x16x32_bf16(
            ahi[mf], bhi[jf], acc[mf][jf], 0, 0, 0);
        acc[mf][jf] = __builtin_amdgcn_mfma_f32_16x16x32_bf16(
            ahi[mf], blo[jf], acc[mf][jf], 0, 0, 0);
        acc[mf][jf] = __builtin_amdgcn_mfma_f32_16x16x32_bf16(
            alo[mf], bhi[jf], acc[mf][jf], 0, 0, 0);
      }
  }

  // bias (D layout: col j = lane&15, rows m = quad*4 + reg)
  #pragma unroll
  for (int jf = 0; jf < 2; jf++) {
    float bj = bias[j0 + wj * 32 + jf * 16 + lm];
    #pragma unroll
    for (int mf = 0; mf < 4; mf++)
      #pragma unroll
      for (int r = 0; r < 4; r++)
        acc[mf][jf][r] += bj;
  }

  if (mode == 2) {
    #pragma unroll
    for (int mf = 0; mf < 4; mf++)
      #pragma unroll
      for (int jf = 0; jf < 2; jf++) {
        int j = j0 + wj * 32 + jf * 16 + lm;
        int mb = m0 + wm * 64 + mf * 16 + quad * 4;
        #pragma unroll
        for (int r = 0; r < 4; r++)
          dst[(size_t)(mb + r) * 256 + j] = acc[mf][jf][r];
      }
  } else {
    const int b = m0 >> 12;
    const int n0 = m0 & 4095;
    #pragma unroll
    for (int mf = 0; mf < 4; mf++)
      #pragma unroll
      for (int jf = 0; jf < 2; jf++) {
        int j = j0 + wj * 32 + jf * 16 + lm;
        int nb = n0 + wm * 64 + mf * 16 + quad * 4;
        float4 o = make_float4(acc[mf][jf][0], acc[mf][jf][1],
                               acc[mf][jf][2], acc[mf][jf][3]);
        *(float4*)(dst + (size_t)(b * 256 + j) * 4096 + nb) = o;
      }
  }
}

// ---------------------------------------------------------------------------
// Radix-2 DIT FFT over 4096 complex points in LDS, 256 threads.
// ---------------------------------------------------------------------------
__device__ inline void fft_stages(cf* X, int tid, float sign)
{
  for (int s = 1; s <= 12; s++) {
    const int half = 1 << (s - 1);
    __syncthreads();
    #pragma unroll 2
    for (int i = 0; i < 8; i++) {
      int t = tid + i * 256;                   // butterfly 0..2047
      int j = t & (half - 1);
      int k = ((t >> (s - 1)) << s) + j;
      float ang = sign * 6.283185307179586f * (float)j / (float)(2 * half);
      float sn, cs;
      __sincosf(ang, &sn, &cs);
      cf a = X[k];
      cf b = X[k + half];
      float tbx = cs * b.x - sn * b.y;
      float tby = cs * b.y + sn * b.x;
      X[k]        = make_float2(a.x + tbx, a.y + tby);
      X[k + half] = make_float2(a.x - tbx, a.y - tby);
    }
  }
  __syncthreads();
}

// K2: forward FFT of TWO real columns packed as one complex FFT.
__global__ __launch_bounds__(256) void fft_fwd(
    const float* __restrict__ src_base, cf* __restrict__ dst_base)
{
  __shared__ cf X[4096];
  const int c0 = blockIdx.x * 2;
  const float* s0 = src_base + (size_t)c0 * 4096;
  const float* s1 = s0 + 4096;
  const int tid = threadIdx.x;
  #pragma unroll
  for (int i = 0; i < 16; i++) {
    int n = tid + i * 256;
    int r = __brev((unsigned)n) >> 20;
    X[r] = make_float2(s0[n], s1[n]);
  }
  fft_stages(X, tid, -1.0f);
  cf* d0 = dst_base + (size_t)c0 * NFREQ;
  cf* d1 = d0 + NFREQ;
  for (int f = tid; f <= 2048; f += 256) {
    cf Zf = X[f];
    cf Zm = X[(4096 - f) & 4095];
    d0[f] = make_float2(0.5f * (Zf.x + Zm.x), 0.5f * (Zf.y - Zm.y));
    d1[f] = make_float2(0.5f * (Zf.y + Zm.y), 0.5f * (Zm.x - Zf.x));
  }
}

// ---------------------------------------------------------------------------
// K3: frequency-domain circular conv along d (32), register-resident.
// One thread per frequency f; in-place over Qf.
// ---------------------------------------------------------------------------
__global__ __launch_bounds__(256) void freq_conv(
    cf* Qf, const cf* __restrict__ Kf)
{
  const int f = blockIdx.x * 256 + threadIdx.x;
  const int bh = blockIdx.y;
  if (f > 2048) return;
  const size_t base = (size_t)bh * 32 * NFREQ + f;
  cf q[32], k[32];
  #pragma unroll
  for (int e = 0; e < 32; e++) {
    q[e] = Qf[base + (size_t)e * NFREQ];
    k[e] = Kf[base + (size_t)e * NFREQ];
  }
  #pragma unroll
  for (int d = 0; d < 32; d++) {
    float ax = 0.0f, ay = 0.0f;
    #pragma unroll
    for (int e = 0; e < 32; e++) {
      cf a = q[e];
      cf b = k[(d - e) & 31];
      ax += a.x * b.x - a.y * b.y;
      ay += a.x * b.y + a.y * b.x;
    }
    Qf[base + (size_t)d * NFREQ] = make_float2(ax, ay);
  }
}

// K4: inverse FFT of TWO hermitian half-spectra packed: Z = C1 + i*C2.
__global__ __launch_bounds__(256) void fft_inv(
    const cf* __restrict__ Cf, float* __restrict__ attn)
{
  __shared__ cf X[4096];
  const int c0 = blockIdx.x * 2;
  const cf* s0 = Cf + (size_t)c0 * NFREQ;
  const cf* s1 = s0 + NFREQ;
  const int tid = threadIdx.x;
  for (int f = tid; f <= 2048; f += 256) {
    cf c1 = s0[f];
    cf c2 = s1[f];
    int r = __brev((unsigned)f) >> 20;
    X[r] = make_float2(c1.x - c2.y, c1.y + c2.x);
    if (f != 0 && f != 2048) {
      int r2 = __brev((unsigned)(4096 - f)) >> 20;
      X[r2] = make_float2(c1.x + c2.y, c2.x - c1.y);
    }
  }
  fft_stages(X, tid, +1.0f);
  float* d0 = attn + (size_t)c0 * 4096;
  float* d1 = d0 + 4096;
  const float inv = 1.0f / 4096.0f;
  #pragma unroll
  for (int i = 0; i < 16; i++) {
    int n = tid + i * 256;
    cf z = X[n];
    d0[n] = z.x * inv;
    d1[n] = z.y * inv;
  }
}

// ---------------------------------------------------------------------------
// K5: softmax over d (32) + value gate + residual + LayerNorm(256)
// ---------------------------------------------------------------------------
__global__ __launch_bounds__(256) void finalize_kernel(
    const float* __restrict__ attn, const float* __restrict__ VL,
    const float* __restrict__ vin, const float* __restrict__ gamma,
    const float* __restrict__ beta, float* __restrict__ out)
{
  __shared__ float At[256][33];
  const int n0 = blockIdx.x * 32;
  const int b = blockIdx.y;
  const int tid = threadIdx.x;
  #pragma unroll
  for (int i = 0; i < 32; i++) {
    int v = tid + i * 256;
    int hd = v >> 5, nn = v & 31;
    At[hd][nn] = attn[(size_t)(b * 256 + hd) * 4096 + n0 + nn];
  }
  __syncthreads();
  const int wave = tid >> 6, lane = tid & 63;
  float g[4], bt[4];
  #pragma unroll
  for (int r = 0; r < 4; r++) { g[r] = gamma[64 * r + lane]; bt[r] = beta[64 * r + lane]; }

  for (int t = 0; t < 8; t++) {
    const int nn = wave * 8 + t;
    const int n = n0 + nn;
    float p[4];
    #pragma unroll
    for (int r = 0; r < 4; r++) {
      float a = At[64 * r + lane][nn];
      float mx = a;
      #pragma unroll
      for (int off = 16; off >= 1; off >>= 1) mx = fmaxf(mx, __shfl_xor(mx, off, 32));
      float e = __expf(a - mx);
      float s = e;
      #pragma unroll
      for (int off = 16; off >= 1; off >>= 1) s += __shfl_xor(s, off, 32);
      p[r] = e / s;
    }
    const size_t base = ((size_t)b * 4096 + n) * 256 + lane;
    float o[4];
    float s1 = 0.0f, s2 = 0.0f;
    #pragma unroll
    for (int r = 0; r < 4; r++) {
      o[r] = VL[base + 64 * r] * p[r] + vin[base + 64 * r];
      s1 += o[r];
      s2 += o[r] * o[r];
    }
    #pragma unroll
    for (int off = 32; off >= 1; off >>= 1) {
      s1 += __shfl_xor(s1, off, 64);
      s2 += __shfl_xor(s2, off, 64);
    }
    float mu = s1 * (1.0f / 256.0f);
    float var = s2 * (1.0f / 256.0f) - mu * mu;
    float rs = rsqrtf(var + 1e-5f);
    #pragma unroll
    for (int r = 0; r < 4; r++)
      out[base + 64 * r] = (o[r] - mu) * rs * g[r] + bt[r];
  }
}

// ---------------------------------------------------------------------------
extern "C" void kernel_launch(void* const* d_in, const int* in_sizes, int n_in,
                              void* d_out, int out_size, void* d_ws, size_t ws_size,
                              hipStream_t stream)
{
  const float* q  = (const float*)d_in[0];
  const float* k  = (const float*)d_in[1];
  const float* v  = (const float*)d_in[2];
  const float* Wq = (const float*)d_in[3];
  const float* bq = (const float*)d_in[4];
  const float* Wk = (const float*)d_in[5];
  const float* bk = (const float*)d_in[6];
  const float* Wv = (const float*)d_in[7];
  const float* bv = (const float*)d_in[8];
  const float* ln_gamma = (const float*)d_in[9];
  const float* ln_beta  = (const float*)d_in[10];
  float* out = (float*)d_out;

  float* ws = (float*)d_ws;
  float* QL = ws;                               // [2048][4096]
  float* KL = QL + (size_t)8388608;             // [2048][4096]
  float* VL = KL + (size_t)8388608;             // [32768][256]
  cf* Qf = (cf*)(VL + (size_t)8388608);         // [2048][2049] complex
  cf* Kf = Qf + (size_t)2048 * NFREQ;           // [2048][2049] complex
  float* attn = QL;                             // reuse QL after fwd FFT

  gemm_proj<<<dim3(256, 4), 256, 0, stream>>>(q, Wq, bq, QL, 0);
  gemm_proj<<<dim3(256, 4), 256, 0, stream>>>(k, Wk, bk, KL, 1);
  gemm_proj<<<dim3(256, 4), 256, 0, stream>>>(v, Wv, bv, VL, 2);

  fft_fwd<<<1024, 256, 0, stream>>>(QL, Qf);
  fft_fwd<<<1024, 256, 0, stream>>>(KL, Kf);

  freq_conv<<<dim3(9, 64), 256, 0, stream>>>(Qf, Kf);

  fft_inv<<<1024, 256, 0, stream>>>(Qf, attn);

  finalize_kernel<<<dim3(128, 8), 256, 0, stream>>>(attn, VL, v, ln_gamma,
                                                    ln_beta, out);
}

// Round 4
// 319.819 us; speedup vs baseline: 1.9810x; 1.1060x over previous
//
#include <hip/hip_runtime.h>

#define NFREQ 2049   // 4096/2 + 1

using cf = float2;
typedef __attribute__((ext_vector_type(8))) short short8;
typedef __attribute__((ext_vector_type(4))) float floatx4;

__device__ inline unsigned short bf16_rne(float x) {
  unsigned u = __float_as_uint(x);
  unsigned r = u + 0x7FFFu + ((u >> 16) & 1u);
  return (unsigned short)(r >> 16);
}
__device__ inline float bf16_to_f(unsigned short h) {
  return __uint_as_float(((unsigned)h) << 16);
}

// ---------------------------------------------------------------------------
// K1: projection GEMM  C = X @ W^T + b  via split-bf16 MFMA (3 passes).
// ---------------------------------------------------------------------------
__global__ __launch_bounds__(256, 4) void gemm_proj(
    const float* __restrict__ X, const float* __restrict__ W,
    const float* __restrict__ bias, float* __restrict__ dst, int mode)
{
  __shared__ __align__(16) unsigned short sm[12416];
  unsigned short* sAhi = sm;            // 4*129*8 = 4128
  unsigned short* sAlo = sm + 4128;
  unsigned short* sBhi = sm + 8256;     // 4*65*8  = 2080
  unsigned short* sBlo = sm + 10336;

  const int tid = threadIdx.x;
  const int m0 = blockIdx.x * 128;
  const int j0 = blockIdx.y * 64;
  const int wave = tid >> 6, lane = tid & 63;
  const int wm = wave & 1, wj = wave >> 1;
  const int lm = lane & 15, quad = lane >> 4;

  floatx4 acc[4][2] = {};

  for (int k0 = 0; k0 < 256; k0 += 32) {
    float4 xa[4], wb[2];
    #pragma unroll
    for (int r = 0; r < 4; r++) {
      int v = tid + r * 256;
      int row = v >> 3, c4 = (v & 7) * 4;
      xa[r] = *(const float4*)(X + (size_t)(m0 + row) * 256 + k0 + c4);
    }
    #pragma unroll
    for (int r = 0; r < 2; r++) {
      int v = tid + r * 256;
      int row = v >> 3, c4 = (v & 7) * 4;
      wb[r] = *(const float4*)(W + (size_t)(j0 + row) * 256 + k0 + c4);
    }
    __syncthreads();
    #pragma unroll
    for (int r = 0; r < 4; r++) {
      int v = tid + r * 256;
      int row = v >> 3, c4 = (v & 7) * 4;
      int q = c4 >> 3, off = c4 & 7;
      float f[4] = {xa[r].x, xa[r].y, xa[r].z, xa[r].w};
      unsigned short h[4], l[4];
      #pragma unroll
      for (int i = 0; i < 4; i++) {
        h[i] = bf16_rne(f[i]);
        l[i] = bf16_rne(f[i] - bf16_to_f(h[i]));
      }
      int idx = ((q * 129 + row) << 3) + off;
      *(uint2*)&sAhi[idx] = make_uint2((unsigned)h[0] | ((unsigned)h[1] << 16),
                                       (unsigned)h[2] | ((unsigned)h[3] << 16));
      *(uint2*)&sAlo[idx] = make_uint2((unsigned)l[0] | ((unsigned)l[1] << 16),
                                       (unsigned)l[2] | ((unsigned)l[3] << 16));
    }
    #pragma unroll
    for (int r = 0; r < 2; r++) {
      int v = tid + r * 256;
      int row = v >> 3, c4 = (v & 7) * 4;
      int q = c4 >> 3, off = c4 & 7;
      float f[4] = {wb[r].x, wb[r].y, wb[r].z, wb[r].w};
      unsigned short h[4], l[4];
      #pragma unroll
      for (int i = 0; i < 4; i++) {
        h[i] = bf16_rne(f[i]);
        l[i] = bf16_rne(f[i] - bf16_to_f(h[i]));
      }
      int idx = ((q * 65 + row) << 3) + off;
      *(uint2*)&sBhi[idx] = make_uint2((unsigned)h[0] | ((unsigned)h[1] << 16),
                                       (unsigned)h[2] | ((unsigned)h[3] << 16));
      *(uint2*)&sBlo[idx] = make_uint2((unsigned)l[0] | ((unsigned)l[1] << 16),
                                       (unsigned)l[2] | ((unsigned)l[3] << 16));
    }
    __syncthreads();

    short8 ahi[4], alo[4], bhi[2], blo[2];
    #pragma unroll
    for (int mf = 0; mf < 4; mf++) {
      int row = wm * 64 + mf * 16 + lm;
      int idx = ((quad * 129 + row) << 3);
      ahi[mf] = *(const short8*)&sAhi[idx];
      alo[mf] = *(const short8*)&sAlo[idx];
    }
    #pragma unroll
    for (int jf = 0; jf < 2; jf++) {
      int row = wj * 32 + jf * 16 + lm;
      int idx = ((quad * 65 + row) << 3);
      bhi[jf] = *(const short8*)&sBhi[idx];
      blo[jf] = *(const short8*)&sBlo[idx];
    }
    #pragma unroll
    for (int mf = 0; mf < 4; mf++)
      #pragma unroll
      for (int jf = 0; jf < 2; jf++) {
        acc[mf][jf] = __builtin_amdgcn_mfma_f32_16x16x32_bf16(
            ahi[mf], bhi[jf], acc[mf][jf], 0, 0, 0);
        acc[mf][jf] = __builtin_amdgcn_mfma_f32_16x16x32_bf16(
            ahi[mf], blo[jf], acc[mf][jf], 0, 0, 0);
        acc[mf][jf] = __builtin_amdgcn_mfma_f32_16x16x32_bf16(
            alo[mf], bhi[jf], acc[mf][jf], 0, 0, 0);
      }
  }

  #pragma unroll
  for (int jf = 0; jf < 2; jf++) {
    float bj = bias[j0 + wj * 32 + jf * 16 + lm];
    #pragma unroll
    for (int mf = 0; mf < 4; mf++)
      #pragma unroll
      for (int r = 0; r < 4; r++)
        acc[mf][jf][r] += bj;
  }

  if (mode == 2) {
    #pragma unroll
    for (int mf = 0; mf < 4; mf++)
      #pragma unroll
      for (int jf = 0; jf < 2; jf++) {
        int j = j0 + wj * 32 + jf * 16 + lm;
        int mb = m0 + wm * 64 + mf * 16 + quad * 4;
        #pragma unroll
        for (int r = 0; r < 4; r++)
          dst[(size_t)(mb + r) * 256 + j] = acc[mf][jf][r];
      }
  } else {
    const int b = m0 >> 12;
    const int n0 = m0 & 4095;
    #pragma unroll
    for (int mf = 0; mf < 4; mf++)
      #pragma unroll
      for (int jf = 0; jf < 2; jf++) {
        int j = j0 + wj * 32 + jf * 16 + lm;
        int nb = n0 + wm * 64 + mf * 16 + quad * 4;
        float4 o = make_float4(acc[mf][jf][0], acc[mf][jf][1],
                               acc[mf][jf][2], acc[mf][jf][3]);
        *(float4*)(dst + (size_t)(b * 256 + j) * 4096 + nb) = o;
      }
  }
}

// ---------------------------------------------------------------------------
// Radix-4 DIT FFT over 4096 complex points in LDS (swizzled), 256 threads.
// Input loaded digit(base-4)-reversed; output natural order.
// Swizzle p(i) = i + (i>>4) + (i>>8): spreads linear, stride-4^k, and
// stride-64 digit-reversed access patterns evenly over the 16 element-banks.
// ---------------------------------------------------------------------------
#define FFT_LDS 4368   // swz(4095) = 4365

__device__ inline int swz(int i) { return i + (i >> 4) + (i >> 8); }
__device__ inline int digrev4(int n) {           // 12-bit base-4 digit reverse
  int b = __brev((unsigned)n) >> 20;
  return ((b & 0x555) << 1) | ((b & 0xAAA) >> 1);
}

template<int SIGN>   // -1 forward, +1 inverse
__device__ inline void fft4_stages(cf* X, int tid)
{
  #pragma unroll
  for (int s = 0; s < 6; s++) {
    const int q = 1 << (2 * s);                  // 1,4,16,64,256,1024
    __syncthreads();
    #pragma unroll
    for (int r = 0; r < 4; r++) {
      int t = tid + r * 256;                     // butterfly id 0..1023
      int j = t & (q - 1);
      int base = ((t >> (2 * s)) << (2 * s + 2)) + j;
      cf a = X[swz(base)];
      cf b = X[swz(base + q)];
      cf c = X[swz(base + 2 * q)];
      cf d = X[swz(base + 3 * q)];
      float th = (float)SIGN * 6.283185307179586f * (float)j / (float)(4 * q);
      float s1, c1, s2, c2, s3, c3;
      __sincosf(th, &s1, &c1);
      __sincosf(2.0f * th, &s2, &c2);
      __sincosf(3.0f * th, &s3, &c3);
      cf bt = make_float2(c1 * b.x - s1 * b.y, c1 * b.y + s1 * b.x);
      cf ct = make_float2(c2 * c.x - s2 * c.y, c2 * c.y + s2 * c.x);
      cf dt = make_float2(c3 * d.x - s3 * d.y, c3 * d.y + s3 * d.x);
      cf e0 = make_float2(a.x + ct.x, a.y + ct.y);
      cf e1 = make_float2(a.x - ct.x, a.y - ct.y);
      cf o0 = make_float2(bt.x + dt.x, bt.y + dt.y);
      cf o1 = make_float2(bt.x - dt.x, bt.y - dt.y);
      cf io1 = make_float2(-o1.y, o1.x);         // i*o1
      X[swz(base)]         = make_float2(e0.x + o0.x, e0.y + o0.y);
      X[swz(base + 2 * q)] = make_float2(e0.x - o0.x, e0.y - o0.y);
      if (SIGN < 0) {
        X[swz(base + q)]     = make_float2(e1.x - io1.x, e1.y - io1.y);
        X[swz(base + 3 * q)] = make_float2(e1.x + io1.x, e1.y + io1.y);
      } else {
        X[swz(base + q)]     = make_float2(e1.x + io1.x, e1.y + io1.y);
        X[swz(base + 3 * q)] = make_float2(e1.x - io1.x, e1.y - io1.y);
      }
    }
  }
  __syncthreads();
}

// K2: forward FFT of TWO real columns packed as one complex FFT.
__global__ __launch_bounds__(256) void fft_fwd(
    const float* __restrict__ src_base, cf* __restrict__ dst_base)
{
  __shared__ cf X[FFT_LDS];
  const int c0 = blockIdx.x * 2;
  const float* s0 = src_base + (size_t)c0 * 4096;
  const float* s1 = s0 + 4096;
  const int tid = threadIdx.x;
  #pragma unroll
  for (int i = 0; i < 16; i++) {
    int n = tid + i * 256;
    X[swz(digrev4(n))] = make_float2(s0[n], s1[n]);
  }
  fft4_stages<-1>(X, tid);
  cf* d0 = dst_base + (size_t)c0 * NFREQ;
  cf* d1 = d0 + NFREQ;
  for (int f = tid; f <= 2048; f += 256) {
    cf Zf = X[swz(f)];
    cf Zm = X[swz((4096 - f) & 4095)];
    d0[f] = make_float2(0.5f * (Zf.x + Zm.x), 0.5f * (Zf.y - Zm.y));
    d1[f] = make_float2(0.5f * (Zf.y + Zm.y), 0.5f * (Zm.x - Zf.x));
  }
}

// ---------------------------------------------------------------------------
// K3: frequency-domain circular conv along d (32), register-resident.
// launch_bounds(256,2): q[32]+k[32] = 128 VGPRs live -> no spilling.
// ---------------------------------------------------------------------------
__global__ __launch_bounds__(256, 2) void freq_conv(
    cf* Qf, const cf* __restrict__ Kf)
{
  const int f = blockIdx.x * 256 + threadIdx.x;
  const int bh = blockIdx.y;
  if (f > 2048) return;
  const size_t base = (size_t)bh * 32 * NFREQ + f;
  cf q[32], k[32];
  #pragma unroll
  for (int e = 0; e < 32; e++) {
    q[e] = Qf[base + (size_t)e * NFREQ];
    k[e] = Kf[base + (size_t)e * NFREQ];
  }
  #pragma unroll
  for (int d = 0; d < 32; d++) {
    float ax = 0.0f, ay = 0.0f;
    #pragma unroll
    for (int e = 0; e < 32; e++) {
      cf a = q[e];
      cf b = k[(d - e) & 31];
      ax += a.x * b.x - a.y * b.y;
      ay += a.x * b.y + a.y * b.x;
    }
    Qf[base + (size_t)d * NFREQ] = make_float2(ax, ay);
  }
}

// K4: inverse FFT of TWO hermitian half-spectra packed: Z = C1 + i*C2.
__global__ __launch_bounds__(256) void fft_inv(
    const cf* __restrict__ Cf, float* __restrict__ attn)
{
  __shared__ cf X[FFT_LDS];
  const int c0 = blockIdx.x * 2;
  const cf* s0 = Cf + (size_t)c0 * NFREQ;
  const cf* s1 = s0 + NFREQ;
  const int tid = threadIdx.x;
  for (int f = tid; f <= 2048; f += 256) {
    cf c1 = s0[f];
    cf c2 = s1[f];
    X[swz(digrev4(f))] = make_float2(c1.x - c2.y, c1.y + c2.x);
    if (f != 0 && f != 2048)
      X[swz(digrev4(4096 - f))] = make_float2(c1.x + c2.y, c2.x - c1.y);
  }
  fft4_stages<+1>(X, tid);
  float* d0 = attn + (size_t)c0 * 4096;
  float* d1 = d0 + 4096;
  const float inv = 1.0f / 4096.0f;
  #pragma unroll
  for (int i = 0; i < 16; i++) {
    int n = tid + i * 256;
    cf z = X[swz(n)];
    d0[n] = z.x * inv;
    d1[n] = z.y * inv;
  }
}

// ---------------------------------------------------------------------------
// K5: softmax over d (32) + value gate + residual + LayerNorm(256)
// ---------------------------------------------------------------------------
__global__ __launch_bounds__(256) void finalize_kernel(
    const float* __restrict__ attn, const float* __restrict__ VL,
    const float* __restrict__ vin, const float* __restrict__ gamma,
    const float* __restrict__ beta, float* __restrict__ out)
{
  __shared__ float At[256][33];
  const int n0 = blockIdx.x * 32;
  const int b = blockIdx.y;
  const int tid = threadIdx.x;
  #pragma unroll
  for (int i = 0; i < 32; i++) {
    int v = tid + i * 256;
    int hd = v >> 5, nn = v & 31;
    At[hd][nn] = attn[(size_t)(b * 256 + hd) * 4096 + n0 + nn];
  }
  __syncthreads();
  const int wave = tid >> 6, lane = tid & 63;
  float g[4], bt[4];
  #pragma unroll
  for (int r = 0; r < 4; r++) { g[r] = gamma[64 * r + lane]; bt[r] = beta[64 * r + lane]; }

  for (int t = 0; t < 8; t++) {
    const int nn = wave * 8 + t;
    const int n = n0 + nn;
    float p[4];
    #pragma unroll
    for (int r = 0; r < 4; r++) {
      float a = At[64 * r + lane][nn];
      float mx = a;
      #pragma unroll
      for (int off = 16; off >= 1; off >>= 1) mx = fmaxf(mx, __shfl_xor(mx, off, 32));
      float e = __expf(a - mx);
      float s = e;
      #pragma unroll
      for (int off = 16; off >= 1; off >>= 1) s += __shfl_xor(s, off, 32);
      p[r] = e / s;
    }
    const size_t base = ((size_t)b * 4096 + n) * 256 + lane;
    float o[4];
    float s1 = 0.0f, s2 = 0.0f;
    #pragma unroll
    for (int r = 0; r < 4; r++) {
      o[r] = VL[base + 64 * r] * p[r] + vin[base + 64 * r];
      s1 += o[r];
      s2 += o[r] * o[r];
    }
    #pragma unroll
    for (int off = 32; off >= 1; off >>= 1) {
      s1 += __shfl_xor(s1, off, 64);
      s2 += __shfl_xor(s2, off, 64);
    }
    float mu = s1 * (1.0f / 256.0f);
    float var = s2 * (1.0f / 256.0f) - mu * mu;
    float rs = rsqrtf(var + 1e-5f);
    #pragma unroll
    for (int r = 0; r < 4; r++)
      out[base + 64 * r] = (o[r] - mu) * rs * g[r] + bt[r];
  }
}

// ---------------------------------------------------------------------------
extern "C" void kernel_launch(void* const* d_in, const int* in_sizes, int n_in,
                              void* d_out, int out_size, void* d_ws, size_t ws_size,
                              hipStream_t stream)
{
  const float* q  = (const float*)d_in[0];
  const float* k  = (const float*)d_in[1];
  const float* v  = (const float*)d_in[2];
  const float* Wq = (const float*)d_in[3];
  const float* bq = (const float*)d_in[4];
  const float* Wk = (const float*)d_in[5];
  const float* bk = (const float*)d_in[6];
  const float* Wv = (const float*)d_in[7];
  const float* bv = (const float*)d_in[8];
  const float* ln_gamma = (const float*)d_in[9];
  const float* ln_beta  = (const float*)d_in[10];
  float* out = (float*)d_out;

  float* ws = (float*)d_ws;
  float* QL = ws;                               // [2048][4096]
  float* KL = QL + (size_t)8388608;             // [2048][4096]
  float* VL = KL + (size_t)8388608;             // [32768][256]
  cf* Qf = (cf*)(VL + (size_t)8388608);         // [2048][2049] complex
  cf* Kf = Qf + (size_t)2048 * NFREQ;           // [2048][2049] complex
  float* attn = QL;                             // reuse QL after fwd FFT

  gemm_proj<<<dim3(256, 4), 256, 0, stream>>>(q, Wq, bq, QL, 0);
  gemm_proj<<<dim3(256, 4), 256, 0, stream>>>(k, Wk, bk, KL, 1);
  gemm_proj<<<dim3(256, 4), 256, 0, stream>>>(v, Wv, bv, VL, 2);

  fft_fwd<<<1024, 256, 0, stream>>>(QL, Qf);
  fft_fwd<<<1024, 256, 0, stream>>>(KL, Kf);

  freq_conv<<<dim3(9, 64), 256, 0, stream>>>(Qf, Kf);

  fft_inv<<<1024, 256, 0, stream>>>(Qf, attn);

  finalize_kernel<<<dim3(128, 8), 256, 0, stream>>>(attn, VL, v, ln_gamma,
                                                    ln_beta, out);
}